// Round 1
// baseline (53.030 us; speedup 1.0000x reference)
//
#include <hip/hip_runtime.h>
#include <hip/hip_bf16.h>

typedef __attribute__((ext_vector_type(8))) short short8;
typedef __attribute__((ext_vector_type(4))) float floatx4;

#define D_DIM 128
#define K_EXP 2.8853900817779268f   /* 2*log2(e): exp(2s) = 2^(K_EXP*s) */
#define CS 16                        /* column chunks (grid.y) */
#define CTILE 64                     /* columns staged per LDS tile */
#define BLK_ROWS 256                 /* rows per block (4 waves x 64) */
#define NRB 4                        /* 16-row MFMA blocks per wave */

// ---------------- prep: normalize rows -> bf16 Z, fp32 pos dots ----------------
__global__ void prep_kernel(const float* __restrict__ zi,
                            const float* __restrict__ zj,
                            __hip_bfloat16* __restrict__ Zb,
                            float* __restrict__ posdot, int N) {
    int r = blockIdx.x;
    int t = threadIdx.x;  // 0..63, one wave
    const float* pi = zi + (size_t)r * D_DIM;
    const float* pj = zj + (size_t)r * D_DIM;
    float a0 = pi[t], a1 = pi[t + 64];
    float b0 = pj[t], b1 = pj[t + 64];
    float ssi = a0*a0 + a1*a1;
    float ssj = b0*b0 + b1*b1;
    float sij = a0*b0 + a1*b1;
#pragma unroll
    for (int off = 1; off < 64; off <<= 1) {
        ssi += __shfl_xor(ssi, off);
        ssj += __shfl_xor(ssj, off);
        sij += __shfl_xor(sij, off);
    }
    float ni = sqrtf(ssi), nj = sqrtf(ssj);
    float ri = 1.0f / ni, rj = 1.0f / nj;
    __hip_bfloat16* zr0 = Zb + (size_t)r * D_DIM;
    __hip_bfloat16* zr1 = Zb + (size_t)(r + N) * D_DIM;
    zr0[t]      = __float2bfloat16(a0 * ri);
    zr0[t + 64] = __float2bfloat16(a1 * ri);
    zr1[t]      = __float2bfloat16(b0 * rj);
    zr1[t + 64] = __float2bfloat16(b1 * rj);
    if (t == 0) posdot[r] = sij / fmaxf(ni * nj, 1e-8f);
}

// ---------------- main: fused Gram x exp x rowsum ----------------
// grid: (N2/BLK_ROWS, CS); block: 256 threads (4 waves, 64 rows each)
__global__ __launch_bounds__(256, 2)
void main_kernel(const ushort* __restrict__ Zu,
                 float* __restrict__ rowpart, int N2) {
    __shared__ ushort tile[CTILE * D_DIM];   // 16 KB, XOR-swizzled 16B slots

    const int tid  = threadIdx.x;
    const int lane = tid & 63;
    const int wave = tid >> 6;
    const int m    = lane & 15;     // tile row (A) / tile col (B) index
    const int kg   = lane >> 4;     // 0..3 k-group
    const int rx   = blockIdx.x;
    const int cy   = blockIdx.y;
    const int rwave0 = rx * BLK_ROWS + wave * 64;

    // A fragments: 4 row-blocks x 4 k-steps, kept in registers.
    short8 afrag[NRB][4];
#pragma unroll
    for (int rb = 0; rb < NRB; ++rb) {
        const ushort* ap = Zu + (size_t)(rwave0 + rb * 16 + m) * D_DIM + kg * 8;
#pragma unroll
        for (int ks = 0; ks < 4; ++ks)
            afrag[rb][ks] = *(const short8*)(ap + ks * 32);
    }

    float rowacc[NRB][4];
#pragma unroll
    for (int rb = 0; rb < NRB; ++rb)
#pragma unroll
        for (int g = 0; g < 4; ++g) rowacc[rb][g] = 0.0f;

    const int cols_per_chunk = N2 / CS;          // 512
    const int iters = cols_per_chunk / CTILE;    // 8
    const int c0base = cy * cols_per_chunk;

    for (int it = 0; it < iters; ++it) {
        const int c0 = c0base + it * CTILE;
        // stage CTILE rows of Z (64 x 256B) with XOR swizzle on 16B slots
#pragma unroll
        for (int i = 0; i < 4; ++i) {
            int chunk = i * 256 + tid;           // 0..1023
            int row   = chunk >> 4;              // 0..63
            int slot  = chunk & 15;              // 16B slot within the row
            int sslot = slot ^ (row & 7);
            *(short8*)&tile[row * D_DIM + sslot * 8] =
                *(const short8*)&Zu[(size_t)(c0 + row) * D_DIM + slot * 8];
        }
        __syncthreads();

#pragma unroll
        for (int sub = 0; sub < 4; ++sub) {
            const int brow = sub * 16 + m;
            short8 bfrag[4];
#pragma unroll
            for (int ks = 0; ks < 4; ++ks) {
                int slot  = ks * 4 + kg;
                int sslot = slot ^ (brow & 7);
                bfrag[ks] = *(const short8*)&tile[brow * D_DIM + sslot * 8];
            }
            const int cs0 = c0 + sub * 16;
#pragma unroll
            for (int rb = 0; rb < NRB; ++rb) {
                floatx4 acc = {0.f, 0.f, 0.f, 0.f};
#pragma unroll
                for (int ks = 0; ks < 4; ++ks)
                    acc = __builtin_amdgcn_mfma_f32_16x16x32_bf16(
                        afrag[rb][ks], bfrag[ks], acc, 0, 0, 0);
                const bool dsub = (cs0 == rwave0 + rb * 16);  // wave-uniform
#pragma unroll
                for (int g = 0; g < 4; ++g) {
                    float e = exp2f(acc[g] * K_EXP);
                    if (dsub && (kg * 4 + g == m)) e = 0.0f;  // exclude diagonal
                    rowacc[rb][g] += e;
                }
            }
        }
        __syncthreads();
    }

    // reduce across the 16 column lanes (m varies within a kg group)
#pragma unroll
    for (int rb = 0; rb < NRB; ++rb)
#pragma unroll
        for (int g = 0; g < 4; ++g) {
            float v = rowacc[rb][g];
            v += __shfl_xor(v, 1);
            v += __shfl_xor(v, 2);
            v += __shfl_xor(v, 4);
            v += __shfl_xor(v, 8);
            if (m == 0) {
                int grow = rwave0 + rb * 16 + kg * 4 + g;
                rowpart[(size_t)cy * N2 + grow] = v;
            }
        }
}

// ---------------- finalize: denom -> loss mean ----------------
__global__ void finalize_kernel(const float* __restrict__ rowpart,
                                const float* __restrict__ posdot,
                                float* __restrict__ out, int N2, int NP) {
    __shared__ float red[16];
    int tid = threadIdx.x;   // 0..1023
    float s = 0.0f;
    for (int r = tid; r < N2; r += 1024) {
        float denom = 0.0f;
#pragma unroll
        for (int q = 0; q < CS; ++q) denom += rowpart[(size_t)q * N2 + r];
        float pos = posdot[r < NP ? r : r - NP];
        s += logf(denom) - 2.0f * pos;   // -log(num/denom), 1/t = 2
    }
#pragma unroll
    for (int off = 1; off < 64; off <<= 1) s += __shfl_xor(s, off);
    if ((tid & 63) == 0) red[tid >> 6] = s;
    __syncthreads();
    if (tid < 64) {
        float v = (tid < 16) ? red[tid] : 0.0f;
#pragma unroll
        for (int off = 1; off < 16; off <<= 1) v += __shfl_xor(v, off);
        if (tid == 0) out[0] = v / (float)N2;
    }
}

extern "C" void kernel_launch(void* const* d_in, const int* in_sizes, int n_in,
                              void* d_out, int out_size, void* d_ws, size_t ws_size,
                              hipStream_t stream) {
    const float* zi = (const float*)d_in[0];
    const float* zj = (const float*)d_in[1];
    const int N  = in_sizes[0] / D_DIM;   // 4096
    const int N2 = 2 * N;                 // 8192

    char* w = (char*)d_ws;
    __hip_bfloat16* Zb = (__hip_bfloat16*)w;
    size_t zb_bytes = (size_t)N2 * D_DIM * sizeof(__hip_bfloat16);   // 2 MB
    float* posdot  = (float*)(w + zb_bytes);                          // 16 KB
    float* rowpart = (float*)(w + zb_bytes + (size_t)N * sizeof(float)); // CS*N2*4

    prep_kernel<<<N, 64, 0, stream>>>(zi, zj, Zb, posdot, N);
    dim3 grid(N2 / BLK_ROWS, CS);
    main_kernel<<<grid, 256, 0, stream>>>((const ushort*)Zb, rowpart, N2);
    finalize_kernel<<<1, 1024, 0, stream>>>(rowpart, posdot, (float*)d_out, N2, N);
}